// Round 4
// baseline (324.400 us; speedup 1.0000x reference)
//
#include <hip/hip_runtime.h>

#define H 128
#define W 128
#define C 128
#define NB 4
#define HW (H * W)

#define PXB 64            // pixels per block (half row)
#define ROWS 8            // staged rows: y-3 .. y+4
#define STR 80            // LDS row stride (floats): cols x0-8 .. x0+71
#define CCH 8             // channels per chunk
#define NCHK (C / CCH)    // 16

typedef float vf2 __attribute__((ext_vector_type(2)));

// Block = 64 consecutive pixels of row y, image n. 1024 blocks x 256 threads.
// Phase 1: 3x3 conv 128->8 offsets (thread = pixel x quarter-channels).
// Phase 2: per 8-channel chunk: stage rows y-3..y+4 into LDS (float4,
//          zero-padded cols), bilinear-gather via LDS (ds_read2-pairable
//          reads), nontemporal stores of the 2x2 output block.
__global__ __launch_bounds__(256) void dcn_fused(
    const float* __restrict__ x, const float* __restrict__ wg,
    const float* __restrict__ bia, float* __restrict__ out) {

  __shared__ float stg[CCH * ROWS * STR];  // 20480 B (overlaid conv partials)
  __shared__ float loff[PXB * 9];          // 2304 B final offsets (pad 9)

  const int t = threadIdx.x;
  const int bx = blockIdx.x;
  // XCD-aware swizzle: XCD = bx&7 gets a contiguous 64-row slice of one image
  const int xcd = bx & 7;
  const int ln = bx >> 3;                  // 0..127
  const int n = xcd >> 1;
  const int y = ((xcd & 1) << 6) | (ln >> 1);
  const int hh = ln & 1;
  const int x0 = hh * PXB;

  const float* xn = x + (size_t)n * C * HW;

  // ---------------- Phase 1: offset conv ----------------------------------
  {
    const int px = t & 63;
    const int cq = t >> 6;                 // quarter of channels
    const int xx = x0 + px;
    int xs[3];
    float cm[3];
#pragma unroll
    for (int j = 0; j < 3; ++j) {
      int xa = xx - 1 + j;
      cm[j] = ((unsigned)xa < (unsigned)W) ? 1.f : 0.f;
      xs[j] = xa < 0 ? 0 : (xa > W - 1 ? W - 1 : xa);
    }
    int ro[3];
    float m[3][3];
#pragma unroll
    for (int r = 0; r < 3; ++r) {
      int yy = y + r - 1;
      float rm = ((unsigned)yy < (unsigned)H) ? 1.f : 0.f;
      int yc = yy < 0 ? 0 : (yy > H - 1 ? H - 1 : yy);
      ro[r] = yc * W;
#pragma unroll
      for (int j = 0; j < 3; ++j) m[r][j] = rm * cm[j];
    }
    float acc[8];
#pragma unroll
    for (int p = 0; p < 8; ++p) acc[p] = 0.f;
#pragma unroll 2
    for (int c0 = cq * 32; c0 < cq * 32 + 32; ++c0) {
      const float* xc = xn + (size_t)c0 * HW;
      float xv[3][3];
#pragma unroll
      for (int r = 0; r < 3; ++r)
#pragma unroll
        for (int j = 0; j < 3; ++j) xv[r][j] = xc[ro[r] + xs[j]] * m[r][j];
      const float* wc = wg + c0 * 9;       // + p*C*9: wave-uniform -> s_load
#pragma unroll
      for (int p = 0; p < 8; ++p) {
        const float* wp = wc + p * C * 9;
#pragma unroll
        for (int r = 0; r < 3; ++r)
#pragma unroll
          for (int j = 0; j < 3; ++j) acc[p] += xv[r][j] * wp[r * 3 + j];
      }
    }
    float* dst = &stg[(cq * 64 + px) * 8];
#pragma unroll
    for (int p = 0; p < 8; ++p) dst[p] = acc[p];
  }
  __syncthreads();

  // ---------------- reduce 4 partials + bias ------------------------------
  for (int i = t; i < PXB * 8; i += 256) {
    int px = i >> 3, p = i & 7;
    float s = bia[p];
#pragma unroll
    for (int g = 0; g < 4; ++g) s += stg[((g * 64 + px) << 3) + p];
    loff[px * 9 + p] = s;
  }
  __syncthreads();

  // ---------------- per-thread sampler params (channel-invariant) ---------
  const int spx = t & 63;
  const int csel = t >> 6;                 // channels {csel, csel+4} per chunk
  const int xx2 = x0 + spx;
  int vadr[4];
  float w00[4], w01[4], w10[4], w11[4];
  bool fast = true;
#pragma unroll
  for (int p = 0; p < 4; ++p) {
    float sy = (float)y + loff[spx * 9 + 2 * p];
    float sx = (float)xx2 + loff[spx * 9 + 2 * p + 1];
    float y0f = floorf(sy), x0f = floorf(sx);
    float wy1 = sy - y0f, wx1 = sx - x0f;
    int iy0 = (int)y0f, ix0 = (int)x0f;
    float vy0 = ((unsigned)iy0 < (unsigned)H) ? 1.f : 0.f;
    float vy1 = ((unsigned)(iy0 + 1) < (unsigned)H) ? 1.f : 0.f;
    float vx0 = ((unsigned)ix0 < (unsigned)W) ? 1.f : 0.f;
    float vx1 = ((unsigned)(ix0 + 1) < (unsigned)W) ? 1.f : 0.f;
    w00[p] = (1.f - wy1) * (1.f - wx1) * vy0 * vx0;
    w01[p] = (1.f - wy1) * wx1 * vy0 * vx1;
    w10[p] = wy1 * (1.f - wx1) * vy1 * vx0;
    w11[p] = wy1 * wx1 * vy1 * vx1;
    int r0 = iy0 - (y - 3);
    int cs = ix0 - (x0 - 8);
    // fast iff the corner pair lies in the staged window OR its weights are 0
    bool okr = (r0 >= 0 && r0 <= ROWS - 2) || (iy0 > H - 1) || (iy0 + 1 < 0);
    bool okc = (cs >= 0 && cs <= STR - 2) || (ix0 > W - 1) || (ix0 + 1 < 0);
    fast = fast && okr && okc;
    r0 = r0 < 0 ? 0 : (r0 > ROWS - 2 ? ROWS - 2 : r0);
    cs = cs < 0 ? 0 : (cs > STR - 2 ? STR - 2 : cs);
    vadr[p] = r0 * STR + cs;
  }

  float* outn = out + (size_t)n * C * 4 * HW;

  // ---------------- Phase 2: chunk loop -----------------------------------
  for (int k = 0; k < NCHK; ++k) {
    __syncthreads();  // previous chunk's gathers done before restaging
    // stage: 8 ch x 8 rows x 20 float4 (zero-fill OOB cols, clamp OOB rows)
    for (int i = t; i < CCH * ROWS * (STR / 4); i += 256) {
      int c = i / (ROWS * (STR / 4));
      int rm = i - c * (ROWS * (STR / 4));
      int r = rm / (STR / 4);
      int sg = rm - r * (STR / 4);
      int gy = y - 3 + r;
      gy = gy < 0 ? 0 : (gy > H - 1 ? H - 1 : gy);
      int gc = x0 - 8 + 4 * sg;
      float4 v = make_float4(0.f, 0.f, 0.f, 0.f);
      if ((unsigned)gc <= (unsigned)(W - 4))
        v = *(const float4*)(xn + (size_t)(k * CCH + c) * HW + gy * W + gc);
      *(float4*)&stg[(c * ROWS + r) * STR + 4 * sg] = v;
    }
    __syncthreads();

    if (fast) {
#pragma unroll
      for (int j = 0; j < 2; ++j) {
        const int c = csel + 4 * j;
        const float* cb = &stg[c * ROWS * STR];
        float s[4];
#pragma unroll
        for (int p = 0; p < 4; ++p) {
          float v00 = cb[vadr[p]];          // ds_read2 pair (0, +1)
          float v01 = cb[vadr[p] + 1];
          float v10 = cb[vadr[p] + STR];    // ds_read2 pair (+80, +81)
          float v11 = cb[vadr[p] + STR + 1];
          s[p] = w00[p] * v00 + w01[p] * v01 + w10[p] * v10 + w11[p] * v11;
        }
        float* oc = outn + (size_t)(k * CCH + c) * 4 * HW + 4 * y * W + 2 * xx2;
        vf2 r0v = {s[0], s[1]};
        vf2 r1v = {s[2], s[3]};
        __builtin_nontemporal_store(r0v, (vf2*)oc);
        __builtin_nontemporal_store(r1v, (vf2*)(oc + 2 * W));
      }
    } else {
      // slow path: global gather with full clamping (rare / never on real data)
#pragma unroll
      for (int j = 0; j < 2; ++j) {
        const int c = csel + 4 * j;
        const float* xc = xn + (size_t)(k * CCH + c) * HW;
        float s[4];
#pragma unroll
        for (int p = 0; p < 4; ++p) {
          float sy = (float)y + loff[spx * 9 + 2 * p];
          float sx = (float)xx2 + loff[spx * 9 + 2 * p + 1];
          int iy0 = (int)floorf(sy), ix0 = (int)floorf(sx);
          int iy1 = iy0 + 1, ix1 = ix0 + 1;
          int cy0 = iy0 < 0 ? 0 : (iy0 > H - 1 ? H - 1 : iy0);
          int cy1 = iy1 < 0 ? 0 : (iy1 > H - 1 ? H - 1 : iy1);
          int cx0 = ix0 < 0 ? 0 : (ix0 > W - 1 ? W - 1 : ix0);
          int cx1 = ix1 < 0 ? 0 : (ix1 > W - 1 ? W - 1 : ix1);
          s[p] = w00[p] * xc[cy0 * W + cx0] + w01[p] * xc[cy0 * W + cx1] +
                 w10[p] * xc[cy1 * W + cx0] + w11[p] * xc[cy1 * W + cx1];
        }
        float* oc = outn + (size_t)(k * CCH + c) * 4 * HW + 4 * y * W + 2 * xx2;
        vf2 r0v = {s[0], s[1]};
        vf2 r1v = {s[2], s[3]};
        __builtin_nontemporal_store(r0v, (vf2*)oc);
        __builtin_nontemporal_store(r1v, (vf2*)(oc + 2 * W));
      }
    }
  }
}

extern "C" void kernel_launch(void* const* d_in, const int* in_sizes, int n_in,
                              void* d_out, int out_size, void* d_ws, size_t ws_size,
                              hipStream_t stream) {
  const float* x = (const float*)d_in[0];
  const float* w = (const float*)d_in[1];
  const float* b = (const float*)d_in[2];
  float* out = (float*)d_out;
  (void)d_ws; (void)ws_size;

  dim3 grid(NB * H * 2), block(256);
  dcn_fused<<<grid, block, 0, stream>>>(x, w, b, out);
}